// Round 5
// baseline (69.725 us; speedup 1.0000x reference)
//
#include <hip/hip_runtime.h>
#include <hip/hip_fp16.h>
#include <math.h>

constexpr int D    = 1024;
constexpr int NEXP = 4;
constexpr int TOPK = 32;
constexpr int EPP  = 2048;   // entries per expert
constexpr int TB   = 8;      // tokens per attn chunk (2 per wave, 4 waves)
constexpr int BPE  = 128;    // attn blocks per expert
constexpr int CSTR = 16;     // counter padding in ints (64B cachelines)

using pk_t = decltype(__builtin_amdgcn_cvt_pkrtz(0.f, 0.f));
__device__ __forceinline__ unsigned pk2(float a, float b) {
    return __builtin_bit_cast(unsigned, __builtin_amdgcn_cvt_pkrtz(a, b));
}
__device__ __forceinline__ __half2 as_hh2(unsigned u) { return __builtin_bit_cast(__half2, u); }
__device__ __forceinline__ float fdot2u(unsigned a, unsigned b, float c) {
    return __builtin_amdgcn_fdot2(__builtin_bit_cast(pk_t, a),
                                  __builtin_bit_cast(pk_t, b), c, false);
}

// ---------------- Phase 1: router + slice f16 prep ----------------
// 1024 threads = 16 waves, 2 tokens/wave -> 32 tokens/block.
// Blocks 0..31 additionally convert the 4 expert slices (128 rows) to a
// pre-permuted f16 copy in d_ws: row r -> [half0: dims with (d>>3)&1==0]
// [half1: rest], each half 1024B, dim d at byte (d>>4)*16 + (d&7)*2.
__global__ __launch_bounds__(1024) void router_kernel(
    const float* __restrict__ h, const float* __restrict__ lts,
    const float* __restrict__ Wr, const float* __restrict__ br,
    float* __restrict__ out_ew, int* __restrict__ cnt, int* __restrict__ list,
    unsigned char* __restrict__ lts16, int ntok)
{
    const int tid  = threadIdx.x;
    const int wid  = tid >> 6;
    const int lane = tid & 63;

    // ---- slice prep: 32 blocks x 4 rows, 1 float4 per thread ----
    if (blockIdx.x < 32) {
        const int r  = blockIdx.x * 4 + (tid >> 8);   // global f16 row 0..127
        const int e  = r >> 5, ri = r & 31;
        const int q  = tid & 255;                      // float4 index in row
        const float4 v = reinterpret_cast<const float4*>(lts)[(size_t)(e * EPP + ri) * 256 + q];
        const int d0 = q << 2;
        unsigned char* dst = lts16 + (size_t)r * 2048 + ((d0 & 8) ? 1024 : 0)
                           + ((d0 >> 4) << 4) + ((d0 & 7) << 1);
        *reinterpret_cast<uint2*>(dst) = make_uint2(pk2(v.x, v.y), pk2(v.z, v.w));
    }

    __shared__ int lds_cnt[NEXP];
    __shared__ int lds_base[NEXP];
    if (tid < NEXP) lds_cnt[tid] = 0;
    __syncthreads();

    const float4* h4 = reinterpret_cast<const float4*>(h);
    const float4* w4 = reinterpret_cast<const float4*>(Wr);

    float4 wf[NEXP][4];
    #pragma unroll
    for (int e = 0; e < NEXP; ++e)
        #pragma unroll
        for (int i = 0; i < 4; ++i)
            wf[e][i] = w4[e * 256 + lane + 64 * i];
    const float bb0 = br[0], bb1 = br[1], bb2 = br[2], bb3 = br[3];

    int mybi[2] = {0, 0}, myrank[2] = {0, 0}, mytok[2] = {-1, -1};

    #pragma unroll
    for (int t = 0; t < 2; ++t) {
        const int tok = blockIdx.x * 32 + wid * 2 + t;
        if (tok < ntok) {
            float acc[NEXP] = {0.f, 0.f, 0.f, 0.f};
            #pragma unroll
            for (int i = 0; i < 4; ++i) {
                const float4 a = h4[(size_t)tok * 256 + lane + 64 * i];
                #pragma unroll
                for (int e = 0; e < NEXP; ++e)
                    acc[e] += a.x * wf[e][i].x + a.y * wf[e][i].y
                            + a.z * wf[e][i].z + a.w * wf[e][i].w;
            }
            #pragma unroll
            for (int m = 1; m < 64; m <<= 1)
                #pragma unroll
                for (int e = 0; e < NEXP; ++e) acc[e] += __shfl_xor(acc[e], m);

            const float l0 = acc[0] + bb0, l1 = acc[1] + bb1,
                        l2 = acc[2] + bb2, l3 = acc[3] + bb3;
            const float lm = fmaxf(fmaxf(l0, l1), fmaxf(l2, l3));
            const float e0 = __expf(l0 - lm), e1 = __expf(l1 - lm),
                        e2 = __expf(l2 - lm), e3 = __expf(l3 - lm);
            const float einv = 1.f / (e0 + e1 + e2 + e3);
            if (lane < NEXP) {
                const float ev = (lane == 0) ? e0 : (lane == 1) ? e1 : (lane == 2) ? e2 : e3;
                out_ew[(size_t)tok * NEXP + lane] = ev * einv;
            }
            int bi = 0; float bv = l0;
            if (l1 > bv) { bv = l1; bi = 1; }
            if (l2 > bv) { bv = l2; bi = 2; }
            if (l3 > bv) { bv = l3; bi = 3; }
            if (lane == 0) {
                mybi[t] = bi; mytok[t] = tok;
                myrank[t] = atomicAdd(&lds_cnt[bi], 1);
            }
        }
    }
    __syncthreads();
    if (tid < NEXP) lds_base[tid] = atomicAdd(&cnt[tid * CSTR], lds_cnt[tid]);
    __syncthreads();
    #pragma unroll
    for (int t = 0; t < 2; ++t)
        if (lane == 0 && mytok[t] >= 0)
            list[(size_t)mybi[t] * ntok + lds_base[mybi[t]] + myrank[t]] = mytok[t];
}

// ---------------- Phase 2: grouped attention, cache-direct ----------------
// No LDS, no barriers: each wave reads slice rows (f16, pre-permuted) from
// L1/L2 directly. 512 blocks (128/expert), grid-stride; 2 tokens per wave.
__global__ __launch_bounds__(256) void attn_kernel(
    const float* __restrict__ h, const unsigned char* __restrict__ lts16,
    const int* __restrict__ cnt, const int* __restrict__ list,
    float* __restrict__ out_res, int ntok)
{
    const int e   = blockIdx.x >> 7;          // / BPE
    const int b0  = blockIdx.x & (BPE - 1);
    const int n_e = cnt[e * CSTR];

    const int tid = threadIdx.x;
    const int wid = tid >> 6, lane = tid & 63;
    const float4* h4 = reinterpret_cast<const float4*>(h);
    float4* o4 = reinterpret_cast<float4*>(out_res);
    const unsigned char* sb = lts16 + (size_t)e * 32 * 2048;

    for (int c = b0; c * TB < n_e; c += BPE) {
        const int t0 = c * TB + wid * 2;
        if (t0 >= n_e) continue;
        const bool has1 = (t0 + 1 < n_e);
        const int tokA = list[(size_t)e * ntok + t0];
        const int tokB = has1 ? list[(size_t)e * ntok + t0 + 1] : tokA;

        // h rows: lane owns dims [16*lane, 16*lane+16)
        unsigned hA[8], hB[8];
        #pragma unroll
        for (int i = 0; i < 4; ++i) {
            const float4 a = h4[(size_t)tokA * 256 + lane * 4 + i];
            hA[2 * i] = pk2(a.x, a.y); hA[2 * i + 1] = pk2(a.z, a.w);
            const float4 b = h4[(size_t)tokB * 256 + lane * 4 + i];
            hB[2 * i] = pk2(b.x, b.y); hB[2 * i + 1] = pk2(b.z, b.w);
        }

        // scores: per-lane partials over its 16 dims; p[0..31]=A, p[32..63]=B
        float p[64];
        #pragma unroll
        for (int j = 0; j < 32; ++j) {
            const uint4 va = *reinterpret_cast<const uint4*>(sb + j * 2048 + lane * 16);
            const uint4 vb = *reinterpret_cast<const uint4*>(sb + j * 2048 + 1024 + lane * 16);
            float a = 0.f, b = 0.f;
            a = fdot2u(hA[0], va.x, a); a = fdot2u(hA[1], va.y, a);
            a = fdot2u(hA[2], va.z, a); a = fdot2u(hA[3], va.w, a);
            a = fdot2u(hA[4], vb.x, a); a = fdot2u(hA[5], vb.y, a);
            a = fdot2u(hA[6], vb.z, a); a = fdot2u(hA[7], vb.w, a);
            b = fdot2u(hB[0], va.x, b); b = fdot2u(hB[1], va.y, b);
            b = fdot2u(hB[2], va.z, b); b = fdot2u(hB[3], va.w, b);
            b = fdot2u(hB[4], vb.x, b); b = fdot2u(hB[5], vb.y, b);
            b = fdot2u(hB[6], vb.z, b); b = fdot2u(hB[7], vb.w, b);
            p[j] = a; p[j + 32] = b;
        }

        // fold-reduce: 64 values x 64 lanes -> lane L holds total of value L
        #pragma unroll
        for (int s = 0; s < 6; ++s) {
            const int m = 32 >> s;
            #pragma unroll
            for (int i = 0; i < (32 >> s); ++i) {
                const bool hib  = (lane & m) != 0;
                const float send = hib ? p[i] : p[i + (32 >> s)];
                const float recv = __shfl_xor(send, m);
                p[i] = (hib ? p[i + (32 >> s)] : p[i]) + recv;
            }
        }

        // distributed softmax: lanes 0..31 = token A, 32..63 = token B
        const float x = p[0] * 0.03125f;      // / sqrt(1024)
        float mx = x;
        #pragma unroll
        for (int m = 16; m >= 1; m >>= 1) mx = fmaxf(mx, __shfl_xor(mx, m));
        const float ex = __expf(x - mx);
        float sm = ex;
        #pragma unroll
        for (int m = 16; m >= 1; m >>= 1) sm += __shfl_xor(sm, m);
        const float sOth = __shfl_xor(sm, 32);
        const float invA = 1.f / ((lane < 32) ? sm : sOth);
        const float invB = 1.f / ((lane < 32) ? sOth : sm);

        // weighted sum: broadcast weights, accumulate f16x2
        __half2 aA[8], aB[8];
        #pragma unroll
        for (int i = 0; i < 8; ++i) {
            aA[i] = __float2half2_rn(0.f);
            aB[i] = __float2half2_rn(0.f);
        }
        #pragma unroll
        for (int j = 0; j < 32; ++j) {
            const uint4 va = *reinterpret_cast<const uint4*>(sb + j * 2048 + lane * 16);
            const uint4 vb = *reinterpret_cast<const uint4*>(sb + j * 2048 + 1024 + lane * 16);
            const __half2 wA = __float2half2_rn(__shfl(ex, j));
            const __half2 wB = __float2half2_rn(__shfl(ex, j + 32));
            aA[0] = __hfma2(wA, as_hh2(va.x), aA[0]);
            aA[1] = __hfma2(wA, as_hh2(va.y), aA[1]);
            aA[2] = __hfma2(wA, as_hh2(va.z), aA[2]);
            aA[3] = __hfma2(wA, as_hh2(va.w), aA[3]);
            aA[4] = __hfma2(wA, as_hh2(vb.x), aA[4]);
            aA[5] = __hfma2(wA, as_hh2(vb.y), aA[5]);
            aA[6] = __hfma2(wA, as_hh2(vb.z), aA[6]);
            aA[7] = __hfma2(wA, as_hh2(vb.w), aA[7]);
            aB[0] = __hfma2(wB, as_hh2(va.x), aB[0]);
            aB[1] = __hfma2(wB, as_hh2(va.y), aB[1]);
            aB[2] = __hfma2(wB, as_hh2(va.z), aB[2]);
            aB[3] = __hfma2(wB, as_hh2(va.w), aB[3]);
            aB[4] = __hfma2(wB, as_hh2(vb.x), aB[4]);
            aB[5] = __hfma2(wB, as_hh2(vb.y), aB[5]);
            aB[6] = __hfma2(wB, as_hh2(vb.z), aB[6]);
            aB[7] = __hfma2(wB, as_hh2(vb.w), aB[7]);
        }

        #pragma unroll
        for (int i = 0; i < 4; ++i) {
            float4 o;
            o.x = __low2float(aA[2 * i]) * invA;
            o.y = __high2float(aA[2 * i]) * invA;
            o.z = __low2float(aA[2 * i + 1]) * invA;
            o.w = __high2float(aA[2 * i + 1]) * invA;
            o4[(size_t)tokA * 256 + lane * 4 + i] = o;
        }
        if (has1) {
            #pragma unroll
            for (int i = 0; i < 4; ++i) {
                float4 o;
                o.x = __low2float(aB[2 * i]) * invB;
                o.y = __high2float(aB[2 * i]) * invB;
                o.z = __low2float(aB[2 * i + 1]) * invB;
                o.w = __high2float(aB[2 * i + 1]) * invB;
                o4[(size_t)tokB * 256 + lane * 4 + i] = o;
            }
        }
    }
}

extern "C" void kernel_launch(void* const* d_in, const int* in_sizes, int n_in,
                              void* d_out, int out_size, void* d_ws, size_t ws_size,
                              hipStream_t stream) {
    const float* h   = (const float*)d_in[0];
    const float* lts = (const float*)d_in[1];
    const float* Wr  = (const float*)d_in[2];
    const float* br  = (const float*)d_in[3];

    const int ntok = in_sizes[0] / D;            // b*t = 4096
    float* out_res = (float*)d_out;              // (b,t,d)
    float* out_ew  = out_res + (size_t)ntok * D; // (b,t,NEXP)

    int* cnt  = (int*)d_ws;                      // [NEXP * CSTR] padded counters
    int* list = cnt + NEXP * CSTR;               // [NEXP][ntok]
    unsigned char* lts16 = (unsigned char*)(list + (size_t)NEXP * ntok);  // 256 KB

    (void)hipMemsetAsync(cnt, 0, NEXP * CSTR * sizeof(int), stream);

    const int rblocks = (ntok + 31) / 32;        // 128 (>= 32 needed for prep)
    router_kernel<<<rblocks, 1024, 0, stream>>>(h, lts, Wr, br, out_ew, cnt, list, lts16, ntok);

    attn_kernel<<<NEXP * BPE, 256, 0, stream>>>(h, lts16, cnt, list, out_res, ntok);
}

// Round 6
// 44.680 us; speedup vs baseline: 1.5605x; 1.5605x over previous
//
#include <hip/hip_runtime.h>
#include <hip/hip_fp16.h>
#include <math.h>

constexpr int D    = 1024;
constexpr int NEXP = 4;
constexpr int TOPK = 32;
constexpr int EPP  = 2048;   // entries per expert
constexpr int CSTR = 16;     // counter padding in ints (64B cachelines)

using pk_t = decltype(__builtin_amdgcn_cvt_pkrtz(0.f, 0.f));
typedef _Float16 f16x8 __attribute__((ext_vector_type(8)));
typedef float    f32x4 __attribute__((ext_vector_type(4)));

__device__ __forceinline__ unsigned pk2(float a, float b) {
    return __builtin_bit_cast(unsigned, __builtin_amdgcn_cvt_pkrtz(a, b));
}

// ---------------- Phase 1: router + slice f16 prep ----------------
// 128 blocks x 1024 threads; 32 tokens/block.
// Blocks 0..31:  f16 row-major slice copy  lts16[r][d]   (128 rows x 1024)
// Blocks 32..63: f16 transposed copy       ltsT[e][d][r] (per expert 1024 x 32)
__global__ __launch_bounds__(1024) void router_kernel(
    const float* __restrict__ h, const float* __restrict__ lts,
    const float* __restrict__ Wr, const float* __restrict__ br,
    float* __restrict__ out_ew, int* __restrict__ cnt, int* __restrict__ list,
    _Float16* __restrict__ lts16, _Float16* __restrict__ ltsT, int ntok)
{
    const int tid  = threadIdx.x;
    const int wid  = tid >> 6;
    const int lane = tid & 63;

    if (blockIdx.x < 32) {                  // row-major f16 slice
        const int r = blockIdx.x * 4 + (tid >> 8);     // 0..127
        const int e = r >> 5, ri = r & 31;
        const int q = tid & 255;
        const float4 v = reinterpret_cast<const float4*>(lts)[(size_t)(e * EPP + ri) * 256 + q];
        *reinterpret_cast<uint2*>(lts16 + (size_t)r * D + q * 4) =
            make_uint2(pk2(v.x, v.y), pk2(v.z, v.w));
    } else if (blockIdx.x < 64) {           // transposed f16 slice
        const int r = (blockIdx.x - 32) * 4 + (tid >> 8);
        const int e = r >> 5, ri = r & 31;
        const int q = tid & 255;
        const float4 v = reinterpret_cast<const float4*>(lts)[(size_t)(e * EPP + ri) * 256 + q];
        _Float16* base = ltsT + (size_t)e * D * 32 + (q * 4) * 32 + ri;
        base[0]  = (_Float16)v.x;
        base[32] = (_Float16)v.y;
        base[64] = (_Float16)v.z;
        base[96] = (_Float16)v.w;
    }

    __shared__ int lds_cnt[NEXP];
    __shared__ int lds_base[NEXP];
    if (tid < NEXP) lds_cnt[tid] = 0;
    __syncthreads();

    const float4* h4 = reinterpret_cast<const float4*>(h);
    const float4* w4 = reinterpret_cast<const float4*>(Wr);

    float4 wf[NEXP][4];
    #pragma unroll
    for (int e = 0; e < NEXP; ++e)
        #pragma unroll
        for (int i = 0; i < 4; ++i)
            wf[e][i] = w4[e * 256 + lane + 64 * i];
    const float bb0 = br[0], bb1 = br[1], bb2 = br[2], bb3 = br[3];

    int mybi[2] = {0, 0}, myrank[2] = {0, 0}, mytok[2] = {-1, -1};

    #pragma unroll
    for (int t = 0; t < 2; ++t) {
        const int tok = blockIdx.x * 32 + wid * 2 + t;
        if (tok < ntok) {
            float acc[NEXP] = {0.f, 0.f, 0.f, 0.f};
            #pragma unroll
            for (int i = 0; i < 4; ++i) {
                const float4 a = h4[(size_t)tok * 256 + lane + 64 * i];
                #pragma unroll
                for (int e = 0; e < NEXP; ++e)
                    acc[e] += a.x * wf[e][i].x + a.y * wf[e][i].y
                            + a.z * wf[e][i].z + a.w * wf[e][i].w;
            }
            #pragma unroll
            for (int m = 1; m < 64; m <<= 1)
                #pragma unroll
                for (int e = 0; e < NEXP; ++e) acc[e] += __shfl_xor(acc[e], m);

            const float l0 = acc[0] + bb0, l1 = acc[1] + bb1,
                        l2 = acc[2] + bb2, l3 = acc[3] + bb3;
            const float lm = fmaxf(fmaxf(l0, l1), fmaxf(l2, l3));
            const float e0 = __expf(l0 - lm), e1 = __expf(l1 - lm),
                        e2 = __expf(l2 - lm), e3 = __expf(l3 - lm);
            const float einv = 1.f / (e0 + e1 + e2 + e3);
            if (lane < NEXP) {
                const float ev = (lane == 0) ? e0 : (lane == 1) ? e1 : (lane == 2) ? e2 : e3;
                out_ew[(size_t)tok * NEXP + lane] = ev * einv;
            }
            int bi = 0; float bv = l0;
            if (l1 > bv) { bv = l1; bi = 1; }
            if (l2 > bv) { bv = l2; bi = 2; }
            if (l3 > bv) { bv = l3; bi = 3; }
            if (lane == 0) {
                mybi[t] = bi; mytok[t] = tok;
                myrank[t] = atomicAdd(&lds_cnt[bi], 1);
            }
        }
    }
    __syncthreads();
    if (tid < NEXP) lds_base[tid] = atomicAdd(&cnt[tid * CSTR], lds_cnt[tid]);
    __syncthreads();
    #pragma unroll
    for (int t = 0; t < 2; ++t)
        if (lane == 0 && mytok[t] >= 0)
            list[(size_t)mybi[t] * ntok + lds_base[mybi[t]] + myrank[t]] = mytok[t];
}

// ---------------- Phase 2: MFMA attention ----------------
// One block (256 thr, 4 waves) per 16-token tile of one expert.
// QK: S(16x32) = H·K^T  (redundant per wave, 64 mfma)
// PV: O(16x1024) = P·K  (64 N-tiles split 16/wave, K=32 single mfma each)
__global__ __launch_bounds__(256) void attn_kernel(
    const float* __restrict__ h,
    const _Float16* __restrict__ lts16,   // [128][1024] row-major
    const _Float16* __restrict__ ltsT,    // [4][1024][32] transposed
    const int* __restrict__ cnt, const int* __restrict__ list,
    float* __restrict__ out_res, int ntok)
{
    // block -> (expert, tile)
    int e = -1, tile = 0, acc_t = 0;
    #pragma unroll
    for (int i = 0; i < NEXP; ++i) {
        const int te = (cnt[i * CSTR] + 15) >> 4;
        if (e < 0 && (int)blockIdx.x < acc_t + te) { e = i; tile = blockIdx.x - acc_t; }
        acc_t += te;
    }
    if (e < 0) return;
    const int n_e  = cnt[e * CSTR];
    const int base = tile * 16;

    const int tid  = threadIdx.x;
    const int wid  = tid >> 6;
    const int lane = tid & 63;

    __shared__ __align__(16) unsigned char h_lds[16 * 2048];  // 32 KB, swizzled f16
    __shared__ _Float16 p_lds[4 * 512];                       // per-wave 16x32

    // ---- stage 16 token rows (f32 -> f16) into swizzled LDS ----
    {
        const int r = tid >> 4, c = tid & 15;
        const int idx = base + r;
        const int tokid = list[(size_t)e * ntok + (idx < n_e ? idx : n_e - 1)];
        const float4* src = reinterpret_cast<const float4*>(h + (size_t)tokid * D);
        #pragma unroll
        for (int i = 0; i < 8; ++i) {
            const int g = c + 16 * i;           // 16B granule index (dims g*8..+8)
            const float4 a = src[2 * g];
            const float4 b = src[2 * g + 1];
            uint4 u;
            u.x = pk2(a.x, a.y); u.y = pk2(a.z, a.w);
            u.z = pk2(b.x, b.y); u.w = pk2(b.z, b.w);
            *reinterpret_cast<uint4*>(h_lds + r * 2048 + ((g ^ (r & 7)) << 4)) = u;
        }
    }
    __syncthreads();

    const int rA  = lane & 15;     // token row (A), also col for B/D
    const int g4  = lane >> 4;     // k-group
    const int swz = rA & 7;

    // ---- QK: acc0 = S[:, 0..15], acc1 = S[:, 16..31] ----
    f32x4 acc0 = {0.f, 0.f, 0.f, 0.f}, acc1 = {0.f, 0.f, 0.f, 0.f};
    const _Float16* sliceE = lts16 + (size_t)e * 32 * D;
    {
        const _Float16* b0p = sliceE + (size_t)rA * D + g4 * 8;
        const _Float16* b1p = b0p + 16 * D;
        #pragma unroll
        for (int kc = 0; kc < 32; ++kc) {
            const f16x8 a = *reinterpret_cast<const f16x8*>(
                h_lds + rA * 2048 + ((((kc << 2) | g4) ^ swz) << 4));
            const f16x8 b0 = *reinterpret_cast<const f16x8*>(b0p + kc * 32);
            const f16x8 b1 = *reinterpret_cast<const f16x8*>(b1p + kc * 32);
            acc0 = __builtin_amdgcn_mfma_f32_16x16x32_f16(a, b0, acc0, 0, 0, 0);
            acc1 = __builtin_amdgcn_mfma_f32_16x16x32_f16(a, b1, acc1, 0, 0, 0);
        }
    }

    // ---- softmax per token row (rows live across 16-lane groups) ----
    constexpr float inv32 = 1.f / 32.f;    // 1/sqrt(1024)
    _Float16* pw = p_lds + wid * 512;
    #pragma unroll
    for (int r = 0; r < 4; ++r) {
        float mx = fmaxf(acc0[r], acc1[r]);
        #pragma unroll
        for (int m = 1; m < 16; m <<= 1) mx = fmaxf(mx, __shfl_xor(mx, m));
        const float e0 = __expf((acc0[r] - mx) * inv32);
        const float e1 = __expf((acc1[r] - mx) * inv32);
        float s = e0 + e1;
        #pragma unroll
        for (int m = 1; m < 16; m <<= 1) s += __shfl_xor(s, m);
        const float is = 1.f / s;
        const int tokr = g4 * 4 + r;
        pw[tokr * 32 + rA]      = (_Float16)(e0 * is);
        pw[tokr * 32 + rA + 16] = (_Float16)(e1 * is);
    }

    // ---- PV: A = P (same frag for all N-tiles), B from transposed slice ----
    const f16x8 pa = *reinterpret_cast<const f16x8*>(pw + rA * 32 + g4 * 8);

    // my 4 output tokens (rows g4*4+r) and validity
    int tokid[4]; bool tval[4];
    #pragma unroll
    for (int r = 0; r < 4; ++r) {
        const int idx = base + g4 * 4 + r;
        tval[r]  = (idx < n_e);
        tokid[r] = list[(size_t)e * ntok + (tval[r] ? idx : n_e - 1)];
    }

    const _Float16* ktE = ltsT + (size_t)e * D * 32;
    #pragma unroll
    for (int i = 0; i < 16; ++i) {
        const int dim = (wid * 16 + i) * 16 + rA;
        const f16x8 bk = *reinterpret_cast<const f16x8*>(ktE + (size_t)dim * 32 + g4 * 8);
        f32x4 o = {0.f, 0.f, 0.f, 0.f};
        o = __builtin_amdgcn_mfma_f32_16x16x32_f16(pa, bk, o, 0, 0, 0);
        #pragma unroll
        for (int r = 0; r < 4; ++r)
            if (tval[r]) out_res[(size_t)tokid[r] * D + dim] = o[r];
    }
}

extern "C" void kernel_launch(void* const* d_in, const int* in_sizes, int n_in,
                              void* d_out, int out_size, void* d_ws, size_t ws_size,
                              hipStream_t stream) {
    const float* h   = (const float*)d_in[0];
    const float* lts = (const float*)d_in[1];
    const float* Wr  = (const float*)d_in[2];
    const float* br  = (const float*)d_in[3];

    const int ntok = in_sizes[0] / D;            // b*t = 4096
    float* out_res = (float*)d_out;              // (b,t,d)
    float* out_ew  = out_res + (size_t)ntok * D; // (b,t,NEXP)

    int* cnt  = (int*)d_ws;                      // [NEXP*CSTR] padded counters
    int* list = cnt + NEXP * CSTR;               // [NEXP][ntok]
    _Float16* lts16 = (_Float16*)(list + (size_t)NEXP * ntok);   // 128x1024 f16
    _Float16* ltsT  = lts16 + (size_t)128 * D;                   // 4x1024x32 f16

    (void)hipMemsetAsync(cnt, 0, NEXP * CSTR * sizeof(int), stream);

    const int rblocks = (ntok + 31) / 32;        // 128
    router_kernel<<<rblocks, 1024, 0, stream>>>(h, lts, Wr, br, out_ew, cnt, list,
                                                lts16, ltsT, ntok);

    const int ablocks = ntok / 16 + NEXP;        // 260 (covers per-expert padding)
    attn_kernel<<<ablocks, 256, 0, stream>>>(h, lts16, ltsT, cnt, list, out_res, ntok);
}

// Round 7
// 40.898 us; speedup vs baseline: 1.7048x; 1.0925x over previous
//
#include <hip/hip_runtime.h>
#include <hip/hip_fp16.h>
#include <math.h>

constexpr int D    = 1024;
constexpr int NEXP = 4;
constexpr int EPP  = 2048;   // entries per expert

using pk_t = decltype(__builtin_amdgcn_cvt_pkrtz(0.f, 0.f));
typedef _Float16 f16x8 __attribute__((ext_vector_type(8)));
typedef float    f32x4 __attribute__((ext_vector_type(4)));

__device__ __forceinline__ unsigned pk2(float a, float b) {
    return __builtin_bit_cast(unsigned, __builtin_amdgcn_cvt_pkrtz(a, b));
}

// ---------------- prep: build f16 slice copies ----------------
// 16 blocks x 1024 thr. Block b: expert e = b>>2, rows part*8..part*8+8.
// lts16[128][1024] row-major; ltsT[4][1024][32] transposed (dim-major).
__global__ __launch_bounds__(1024) void prep_kernel(
    const float* __restrict__ lts, _Float16* __restrict__ lts16,
    _Float16* __restrict__ ltsT)
{
    const int e = blockIdx.x >> 2, part = blockIdx.x & 3;
    const int tid = threadIdx.x;
    __shared__ _Float16 s[8 * 1024];   // 16 KB

    const float4* src = reinterpret_cast<const float4*>(lts + ((size_t)e * EPP + part * 8) * D);
    #pragma unroll
    for (int i = 0; i < 2; ++i) {
        const int f = tid + i * 1024;
        const float4 v = src[f];
        *reinterpret_cast<uint2*>(s + f * 4) = make_uint2(pk2(v.x, v.y), pk2(v.z, v.w));
    }
    __syncthreads();

    // row-major copy (coalesced uint4)
    const uint4* s4 = reinterpret_cast<const uint4*>(s);
    uint4* d4 = reinterpret_cast<uint4*>(lts16 + ((size_t)e * 32 + part * 8) * D);
    d4[tid] = s4[tid];

    // transposed copy: thread = dim, 8 k-values -> one uint4 (2-way LDS reads, free)
    _Float16 tmp[8];
    #pragma unroll
    for (int k = 0; k < 8; ++k) tmp[k] = s[k * 1024 + tid];
    *reinterpret_cast<uint4*>(ltsT + (size_t)e * 32768 + (size_t)tid * 32 + part * 8) =
        *reinterpret_cast<const uint4*>(tmp);
}

// ---------------- fused router + attention ----------------
// One block per 16 consecutive tokens, 4 waves. Wave w computes S for
// expert w (all 16 rows); experts exchanged via LDS; P is 16x128 one-hot
// blocks (XOR-swizzled); PV = K=128 (4 chained MFMA per 16-dim tile).
__global__ __launch_bounds__(256) void fused_kernel(
    const float* __restrict__ h,
    const _Float16* __restrict__ lts16,   // [128][1024]
    const _Float16* __restrict__ ltsT,    // [4][1024][32]
    const float* __restrict__ Wr, const float* __restrict__ br,
    float* __restrict__ out_res, float* __restrict__ out_ew, int ntok)
{
    const int tid  = threadIdx.x;
    const int wid  = tid >> 6;
    const int lane = tid & 63;
    const int base = blockIdx.x * 16;

    __shared__ __align__(16) unsigned char h_lds[16 * 2048];  // 32 KB swizzled f16
    __shared__ __align__(16) unsigned char p_lds[16 * 256];   // 4 KB P (16x128 f16)
    __shared__ int experts[16];

    *reinterpret_cast<uint4*>(p_lds + tid * 16) = make_uint4(0, 0, 0, 0);

    // ---- stage 16 h rows -> swizzled f16 LDS ----
    {
        const int r = tid >> 4, c = tid & 15;
        int tok = base + r; if (tok > ntok - 1) tok = ntok - 1;
        const float4* src = reinterpret_cast<const float4*>(h + (size_t)tok * D);
        #pragma unroll
        for (int i = 0; i < 8; ++i) {
            const int g = c + 16 * i;             // 8-dim granule index
            const float4 a = src[2 * g];
            const float4 b = src[2 * g + 1];
            uint4 u;
            u.x = pk2(a.x, a.y); u.y = pk2(a.z, a.w);
            u.z = pk2(b.x, b.y); u.w = pk2(b.z, b.w);
            *reinterpret_cast<uint4*>(h_lds + r * 2048 + ((g ^ (r & 7)) << 4)) = u;
        }
    }

    // ---- router (f32, identical math to prior passing rounds) ----
    {
        const float4* h4 = reinterpret_cast<const float4*>(h);
        const float4* w4 = reinterpret_cast<const float4*>(Wr);
        float4 wf[NEXP][4];
        #pragma unroll
        for (int e = 0; e < NEXP; ++e)
            #pragma unroll
            for (int i = 0; i < 4; ++i)
                wf[e][i] = w4[e * 256 + lane + 64 * i];
        const float bb0 = br[0], bb1 = br[1], bb2 = br[2], bb3 = br[3];

        #pragma unroll
        for (int t = 0; t < 4; ++t) {
            const int tok = base + wid * 4 + t;
            if (tok < ntok) {
                float acc[NEXP] = {0.f, 0.f, 0.f, 0.f};
                #pragma unroll
                for (int i = 0; i < 4; ++i) {
                    const float4 a = h4[(size_t)tok * 256 + lane + 64 * i];
                    #pragma unroll
                    for (int e = 0; e < NEXP; ++e)
                        acc[e] += a.x * wf[e][i].x + a.y * wf[e][i].y
                                + a.z * wf[e][i].z + a.w * wf[e][i].w;
                }
                #pragma unroll
                for (int m = 1; m < 64; m <<= 1)
                    #pragma unroll
                    for (int e = 0; e < NEXP; ++e) acc[e] += __shfl_xor(acc[e], m);
                const float l0 = acc[0] + bb0, l1 = acc[1] + bb1,
                            l2 = acc[2] + bb2, l3 = acc[3] + bb3;
                const float lm = fmaxf(fmaxf(l0, l1), fmaxf(l2, l3));
                const float e0 = __expf(l0 - lm), e1 = __expf(l1 - lm),
                            e2 = __expf(l2 - lm), e3 = __expf(l3 - lm);
                const float einv = 1.f / (e0 + e1 + e2 + e3);
                if (lane < NEXP) {
                    const float ev = (lane == 0) ? e0 : (lane == 1) ? e1 : (lane == 2) ? e2 : e3;
                    out_ew[(size_t)tok * NEXP + lane] = ev * einv;
                }
                int bi = 0; float bv = l0;
                if (l1 > bv) { bv = l1; bi = 1; }
                if (l2 > bv) { bv = l2; bi = 2; }
                if (l3 > bv) { bv = l3; bi = 3; }
                if (lane == 0) experts[wid * 4 + t] = bi;
            } else if (lane == 0) experts[wid * 4 + t] = 0;
        }
    }
    __syncthreads();

    const int rA = lane & 15, g4 = lane >> 4;

    // ---- QK for expert `wid`: S_w = H(16x1024) . K_w^T -> 16x32 ----
    f32x4 s0 = {0.f, 0.f, 0.f, 0.f}, s1 = {0.f, 0.f, 0.f, 0.f};
    {
        const _Float16* b0p = lts16 + (size_t)(wid * 32 + rA) * D + g4 * 8;
        const _Float16* b1p = b0p + 16 * D;
        #pragma unroll
        for (int kc = 0; kc < 32; ++kc) {
            const f16x8 a  = *reinterpret_cast<const f16x8*>(
                h_lds + rA * 2048 + ((((kc << 2) | g4) ^ (rA & 7)) << 4));
            const f16x8 b0 = *reinterpret_cast<const f16x8*>(b0p + kc * 32);
            const f16x8 b1 = *reinterpret_cast<const f16x8*>(b1p + kc * 32);
            s0 = __builtin_amdgcn_mfma_f32_16x16x32_f16(a, b0, s0, 0, 0, 0);
            s1 = __builtin_amdgcn_mfma_f32_16x16x32_f16(a, b1, s1, 0, 0, 0);
        }
    }

    // ---- softmax for rows routed to this wave's expert; write one-hot P ----
    constexpr float inv32 = 1.f / 32.f;   // 1/sqrt(1024)
    #pragma unroll
    for (int r = 0; r < 4; ++r) {
        const int tr = g4 * 4 + r;
        if (experts[tr] == wid) {         // uniform per 16-lane group
            float mx = fmaxf(s0[r], s1[r]);
            #pragma unroll
            for (int m = 1; m < 16; m <<= 1) mx = fmaxf(mx, __shfl_xor(mx, m));
            const float e0 = __expf((s0[r] - mx) * inv32);
            const float e1 = __expf((s1[r] - mx) * inv32);
            float sm = e0 + e1;
            #pragma unroll
            for (int m = 1; m < 16; m <<= 1) sm += __shfl_xor(sm, m);
            const float is = 1.f / sm;
            const int G0 = (wid * 4 + (rA >> 3)) ^ (tr & 7);
            const int G1 = (wid * 4 + 2 + (rA >> 3)) ^ (tr & 7);
            *reinterpret_cast<_Float16*>(p_lds + tr * 256 + G0 * 16 + (rA & 7) * 2) = (_Float16)(e0 * is);
            *reinterpret_cast<_Float16*>(p_lds + tr * 256 + G1 * 16 + (rA & 7) * 2) = (_Float16)(e1 * is);
        }
    }
    __syncthreads();

    // ---- PV: O = P(16x128) . V(128x1024); wave owns dims wid*256..+256 ----
    f16x8 pa[4];
    #pragma unroll
    for (int kc = 0; kc < 4; ++kc)
        pa[kc] = *reinterpret_cast<const f16x8*>(
            p_lds + rA * 256 + ((((kc << 2) | g4) ^ (rA & 7)) << 4));

    int toks[4]; bool tv[4];
    #pragma unroll
    for (int r = 0; r < 4; ++r) { toks[r] = base + g4 * 4 + r; tv[r] = toks[r] < ntok; }

    #pragma unroll
    for (int i = 0; i < 16; ++i) {
        const int dimc = wid * 256 + i * 16 + rA;
        f32x4 o = {0.f, 0.f, 0.f, 0.f};
        #pragma unroll
        for (int kc = 0; kc < 4; ++kc) {
            const f16x8 bk = *reinterpret_cast<const f16x8*>(
                ltsT + ((size_t)kc << 15) + (size_t)dimc * 32 + g4 * 8);
            o = __builtin_amdgcn_mfma_f32_16x16x32_f16(pa[kc], bk, o, 0, 0, 0);
        }
        #pragma unroll
        for (int r = 0; r < 4; ++r)
            if (tv[r]) out_res[(size_t)toks[r] * D + dimc] = o[r];
    }
}

extern "C" void kernel_launch(void* const* d_in, const int* in_sizes, int n_in,
                              void* d_out, int out_size, void* d_ws, size_t ws_size,
                              hipStream_t stream) {
    const float* h   = (const float*)d_in[0];
    const float* lts = (const float*)d_in[1];
    const float* Wr  = (const float*)d_in[2];
    const float* br  = (const float*)d_in[3];

    const int ntok = in_sizes[0] / D;            // b*t = 4096
    float* out_res = (float*)d_out;              // (b,t,d)
    float* out_ew  = out_res + (size_t)ntok * D; // (b,t,NEXP)

    _Float16* lts16 = (_Float16*)d_ws;                    // 128x1024 f16 (256 KB)
    _Float16* ltsT  = lts16 + (size_t)128 * D;            // 4x1024x32 f16 (256 KB)

    prep_kernel<<<16, 1024, 0, stream>>>(lts, lts16, ltsT);
    fused_kernel<<<(ntok + 15) / 16, 256, 0, stream>>>(h, lts16, ltsT, Wr, br,
                                                       out_res, out_ew, ntok);
}

// Round 8
// 39.858 us; speedup vs baseline: 1.7493x; 1.0261x over previous
//
#include <hip/hip_runtime.h>
#include <hip/hip_fp16.h>
#include <math.h>

constexpr int D    = 1024;
constexpr int NEXP = 4;
constexpr int EPP  = 2048;

typedef _Float16 f16x8 __attribute__((ext_vector_type(8)));
typedef float    f32x4 __attribute__((ext_vector_type(4)));

__device__ __forceinline__ unsigned pk2(float a, float b) {
    return __builtin_bit_cast(unsigned, __builtin_amdgcn_cvt_pkrtz(a, b));
}

// ---------------- prep: build f16 slice copies (64 blocks x 256) ----------------
// block -> e = b>>4, part=(b>>2)&3 (8 rows), dc = b&3 (256 dims)
// lts16[128][1024] row-major; ltsT[4][1024][32] dim-major.
__global__ __launch_bounds__(256) void prep_kernel(
    const float* __restrict__ lts, _Float16* __restrict__ lts16,
    _Float16* __restrict__ ltsT)
{
    const int e = blockIdx.x >> 4, part = (blockIdx.x >> 2) & 3, dc = blockIdx.x & 3;
    const int tid = threadIdx.x;
    __shared__ __align__(16) _Float16 s[8][256];

    const float4* src = reinterpret_cast<const float4*>(lts);
    #pragma unroll
    for (int i = 0; i < 2; ++i) {
        const int f = tid + 256 * i;
        const int r = f >> 6, c4 = f & 63;
        const float4 v = src[(size_t)(e * EPP + part * 8 + r) * 256 + dc * 64 + c4];
        *reinterpret_cast<uint2*>(&s[r][c4 * 4]) = make_uint2(pk2(v.x, v.y), pk2(v.z, v.w));
    }
    __syncthreads();

    {   // row-major copy
        const int r = tid >> 5, c = tid & 31;
        *reinterpret_cast<uint4*>(lts16 + (size_t)(e * 32 + part * 8 + r) * D + dc * 256 + c * 8) =
            *reinterpret_cast<const uint4*>(&s[r][c * 8]);
    }
    {   // transposed copy: thread = dim, 8 k-rows -> one uint4
        _Float16 tmp[8];
        #pragma unroll
        for (int k = 0; k < 8; ++k) tmp[k] = s[k][tid];
        *reinterpret_cast<uint4*>(ltsT + ((size_t)e << 15) + (size_t)(dc * 256 + tid) * 32 + part * 8) =
            *reinterpret_cast<const uint4*>(tmp);
    }
}

// ---------------- K1: router + QK + softmax (512 blocks x 8 tokens) ----------------
__global__ __launch_bounds__(256) void qk_kernel(
    const float* __restrict__ h, const _Float16* __restrict__ lts16,
    const float* __restrict__ Wr, const float* __restrict__ br,
    float* __restrict__ out_ew, _Float16* __restrict__ P32,
    int* __restrict__ eidx, int ntok)
{
    const int tid = threadIdx.x, wid = tid >> 6, lane = tid & 63;
    const int base = blockIdx.x * 8;

    __shared__ __align__(16) unsigned char h_lds[8 * 2048];   // 16 KB swizzled f16
    __shared__ int experts[8];

    {   // stage 8 h rows -> swizzled f16 LDS
        const int r = tid >> 5, c = tid & 31;
        int tok = base + r; if (tok > ntok - 1) tok = ntok - 1;
        const float4* src = reinterpret_cast<const float4*>(h + (size_t)tok * D);
        #pragma unroll
        for (int i = 0; i < 4; ++i) {
            const int g = c + 32 * i;             // 8-dim granule
            const float4 a = src[2 * g];
            const float4 b = src[2 * g + 1];
            uint4 u;
            u.x = pk2(a.x, a.y); u.y = pk2(a.z, a.w);
            u.z = pk2(b.x, b.y); u.w = pk2(b.z, b.w);
            *reinterpret_cast<uint4*>(h_lds + r * 2048 + ((g ^ r) << 4)) = u;
        }
    }

    {   // router: wave wid -> tokens base + wid*2 + {0,1} (identical f32 math)
        const float4* h4 = reinterpret_cast<const float4*>(h);
        const float4* w4 = reinterpret_cast<const float4*>(Wr);
        float4 wf[NEXP][4];
        #pragma unroll
        for (int e = 0; e < NEXP; ++e)
            #pragma unroll
            for (int i = 0; i < 4; ++i)
                wf[e][i] = w4[e * 256 + lane + 64 * i];
        const float bb0 = br[0], bb1 = br[1], bb2 = br[2], bb3 = br[3];

        #pragma unroll
        for (int t = 0; t < 2; ++t) {
            const int tok = base + wid * 2 + t;
            if (tok < ntok) {
                float acc[NEXP] = {0.f, 0.f, 0.f, 0.f};
                #pragma unroll
                for (int i = 0; i < 4; ++i) {
                    const float4 a = h4[(size_t)tok * 256 + lane + 64 * i];
                    #pragma unroll
                    for (int e = 0; e < NEXP; ++e)
                        acc[e] += a.x * wf[e][i].x + a.y * wf[e][i].y
                                + a.z * wf[e][i].z + a.w * wf[e][i].w;
                }
                #pragma unroll
                for (int m = 1; m < 64; m <<= 1)
                    #pragma unroll
                    for (int e = 0; e < NEXP; ++e) acc[e] += __shfl_xor(acc[e], m);
                const float l0 = acc[0] + bb0, l1 = acc[1] + bb1,
                            l2 = acc[2] + bb2, l3 = acc[3] + bb3;
                const float lm = fmaxf(fmaxf(l0, l1), fmaxf(l2, l3));
                const float e0 = __expf(l0 - lm), e1 = __expf(l1 - lm),
                            e2 = __expf(l2 - lm), e3 = __expf(l3 - lm);
                const float einv = 1.f / (e0 + e1 + e2 + e3);
                if (lane < NEXP) {
                    const float ev = (lane == 0) ? e0 : (lane == 1) ? e1 : (lane == 2) ? e2 : e3;
                    out_ew[(size_t)tok * NEXP + lane] = ev * einv;
                }
                int bi = 0; float bv = l0;
                if (l1 > bv) { bv = l1; bi = 1; }
                if (l2 > bv) { bv = l2; bi = 2; }
                if (l3 > bv) { bv = l3; bi = 3; }
                if (lane == 0) experts[wid * 2 + t] = bi;
            } else if (lane == 0) experts[wid * 2 + t] = 0;
        }
    }
    __syncthreads();

    const int rA = lane & 15, g4 = lane >> 4, arow = rA & 7;

    // QK for expert `wid`: rows 8..15 duplicate 0..7 (discarded)
    f32x4 s0 = {0.f, 0.f, 0.f, 0.f}, s1 = {0.f, 0.f, 0.f, 0.f};
    const _Float16* b0p = lts16 + (size_t)(wid * 32 + rA) * D + g4 * 8;
    const _Float16* b1p = b0p + 16 * D;
    #pragma unroll
    for (int kc = 0; kc < 32; ++kc) {
        const f16x8 a = *reinterpret_cast<const f16x8*>(
            h_lds + arow * 2048 + ((((kc << 2) | g4) ^ arow) << 4));
        const f16x8 b0 = *reinterpret_cast<const f16x8*>(b0p + kc * 32);
        const f16x8 b1 = *reinterpret_cast<const f16x8*>(b1p + kc * 32);
        s0 = __builtin_amdgcn_mfma_f32_16x16x32_f16(a, b0, s0, 0, 0, 0);
        s1 = __builtin_amdgcn_mfma_f32_16x16x32_f16(a, b1, s1, 0, 0, 0);
    }

    constexpr float inv32 = 1.f / 32.f;    // 1/sqrt(1024)
    #pragma unroll
    for (int r = 0; r < 4; ++r) {
        const int tr = g4 * 4 + r;
        if (tr < 8 && base + tr < ntok && experts[tr] == wid) {  // uniform per 16-lane group
            float mx = fmaxf(s0[r], s1[r]);
            #pragma unroll
            for (int m = 1; m < 16; m <<= 1) mx = fmaxf(mx, __shfl_xor(mx, m));
            const float e0 = __expf((s0[r] - mx) * inv32);
            const float e1 = __expf((s1[r] - mx) * inv32);
            float sm = e0 + e1;
            #pragma unroll
            for (int m = 1; m < 16; m <<= 1) sm += __shfl_xor(sm, m);
            const float is = 1.f / sm;
            const int tok2 = base + tr;
            P32[(size_t)tok2 * 32 + rA]      = (_Float16)(e0 * is);
            P32[(size_t)tok2 * 32 + rA + 16] = (_Float16)(e1 * is);
            if (rA == 0) eidx[tok2] = wid;
        }
    }
}

// ---------------- K2: PV (1024 blocks = 256 tiles x 4 dim-quarters) ----------------
__global__ __launch_bounds__(256) void pv_kernel(
    const _Float16* __restrict__ P32, const int* __restrict__ eidx,
    const _Float16* __restrict__ ltsT, float* __restrict__ out_res, int ntok)
{
    const int tile = blockIdx.x >> 2, q = blockIdx.x & 3;
    const int tid = threadIdx.x, wid = tid >> 6, lane = tid & 63;
    __shared__ __align__(16) unsigned char p_lds[16 * 256];   // 16x128 f16 swizzled

    {   // rebuild one-hot P tile from P32/eidx
        const int r = tid >> 4, c = tid & 15;
        const int tok = tile * 16 + r;
        uint4 v = make_uint4(0, 0, 0, 0);
        if (tok < ntok) {
            const int ex = eidx[tok];
            if ((c >> 2) == ex)
                v = *reinterpret_cast<const uint4*>(P32 + (size_t)tok * 32 + (c & 3) * 8);
        }
        *reinterpret_cast<uint4*>(p_lds + r * 256 + ((c ^ (r & 7)) << 4)) = v;
    }
    __syncthreads();

    const int rA = lane & 15, g4 = lane >> 4;
    f16x8 pa[4];
    #pragma unroll
    for (int kc = 0; kc < 4; ++kc)
        pa[kc] = *reinterpret_cast<const f16x8*>(
            p_lds + rA * 256 + ((((kc << 2) | g4) ^ (rA & 7)) << 4));

    int toks[4];
    #pragma unroll
    for (int r = 0; r < 4; ++r) toks[r] = tile * 16 + g4 * 4 + r;

    #pragma unroll
    for (int i = 0; i < 4; ++i) {
        const int dimc = q * 256 + wid * 64 + i * 16 + rA;
        f32x4 o = {0.f, 0.f, 0.f, 0.f};
        #pragma unroll
        for (int kc = 0; kc < 4; ++kc) {
            const f16x8 bk = *reinterpret_cast<const f16x8*>(
                ltsT + ((size_t)kc << 15) + (size_t)dimc * 32 + g4 * 8);
            o = __builtin_amdgcn_mfma_f32_16x16x32_f16(pa[kc], bk, o, 0, 0, 0);
        }
        #pragma unroll
        for (int r = 0; r < 4; ++r)
            if (toks[r] < ntok) out_res[(size_t)toks[r] * D + dimc] = o[r];
    }
}

extern "C" void kernel_launch(void* const* d_in, const int* in_sizes, int n_in,
                              void* d_out, int out_size, void* d_ws, size_t ws_size,
                              hipStream_t stream) {
    const float* h   = (const float*)d_in[0];
    const float* lts = (const float*)d_in[1];
    const float* Wr  = (const float*)d_in[2];
    const float* br  = (const float*)d_in[3];

    const int ntok = in_sizes[0] / D;            // b*t = 4096
    float* out_res = (float*)d_out;              // (b,t,d)
    float* out_ew  = out_res + (size_t)ntok * D; // (b,t,NEXP)

    _Float16* lts16 = (_Float16*)d_ws;                       // 128x1024 (256 KB)
    _Float16* ltsT  = lts16 + (size_t)128 * D;               // 4x1024x32 (256 KB)
    _Float16* P32   = ltsT + (size_t)NEXP * D * 32;          // ntok x 32 (256 KB)
    int*      eidx  = (int*)(P32 + (size_t)ntok * 32);       // ntok ints (16 KB)

    prep_kernel<<<64, 256, 0, stream>>>(lts, lts16, ltsT);
    qk_kernel<<<(ntok + 7) / 8, 256, 0, stream>>>(h, lts16, Wr, br, out_ew, P32, eidx, ntok);
    pv_kernel<<<((ntok + 15) / 16) * 4, 256, 0, stream>>>(P32, eidx, ltsT, out_res, ntok);
}